// Round 1
// 1552.125 us; speedup vs baseline: 1.1438x; 1.1438x over previous
//
#include <hip/hip_runtime.h>

// MultiHeadAttention fused pipeline, MI355X gfx950.
// B=1, L=4096, D=512 (d_k=d_v=d_model), H=8.
// Inputs fp32, OUTPUTS fp32. Internal GEMM compute: f16 MFMA (fp32 accum).
//
//   W2_h = W_h @ W_h  (double projection folded)
//   q_s = q @ W2q_h  [8,4096,512]; k_s likewise; v_sT stored TRANSPOSED [8,512,4096]
//   S   = q_s k_s^T / sqrt(512): causal quick-path tiles write 0.0f (final attn),
//         diagonal tiles write -inf above diag (consumed by fused softmax+PV)
//   softmax_pv: per 32-row block: online row max/sumexp (pass 1), then
//         exp/normalize -> write attn f32 (OUTPUT 1) + f16 P tile -> MFMA with
//         v_sT -> heads f16 (replaces softmax kernel + heads GEMM)
//   out = heads @ proj_w^T + proj_b + q -> LayerNorm  (OUTPUT 0)
//
// Memory plan:
//   d_out: [0, 8 MiB) out region (doubles as W2 f16 scratch, then lin f32/LN).
//          [8 MiB, +512 MiB) attn f32 (OUTPUT 1).
//   ws:    q_s | k_s | v_sT | heads, all f16: 4 x 32 MiB = 128 MiB exactly.

typedef _Float16 f16;
typedef __attribute__((ext_vector_type(8))) _Float16 half8;
typedef __attribute__((ext_vector_type(4))) float float4v;

#define LSEQ 4096
#define DMODEL 512
#define NHEAD 8
#define BKK 64
#define LDSK (BKK + 8)   // +8 f16 keeps 16B alignment, breaks bank stride

__device__ __forceinline__ half8 load8h(const f16* p) { return *(const half8*)p; }
__device__ __forceinline__ half8 load8h(const float* p) {
    float4 a = *(const float4*)p;
    float4 b = *(const float4*)(p + 4);
    half8 r;
    r[0] = (f16)a.x; r[1] = (f16)a.y; r[2] = (f16)a.z; r[3] = (f16)a.w;
    r[4] = (f16)b.x; r[5] = (f16)b.y; r[6] = (f16)b.z; r[7] = (f16)b.w;
    return r;
}

// ---------------------------------------------------------------------------
// Generic 64x64-tile f16 MFMA GEMM; A/B fp32 or f16 (converted while staging).
// BLAYOUT: 0 = B stored (N x K) row-major; 1 = B stored (K x N) row-major.
// OUTMODE: 0 = f16 out, 1 = f32 out, 2 = scores (scale + causal; quick-path
//          tiles write 0.0f = final attn value), 3 = f16 out TRANSPOSED
//          (C[col*ldC + row], used to produce v_sT).
// KLIMIT : clip contraction at kend = m0+64.
// ---------------------------------------------------------------------------
template<typename TA, typename TB, int BLAYOUT, int OUTMODE, bool KLIMIT>
__launch_bounds__(256)
__global__ void gemm64_kernel(const TA* __restrict__ A,
                              const TB* __restrict__ B,
                              void* __restrict__ Cv,
                              int M, int N, int K,
                              int ldA, int ldB, int ldC,
                              long sA, long sB, long sC,
                              float scale)
{
    const int bz = blockIdx.z;
    const int n0 = blockIdx.x * 64;
    const int m0 = blockIdx.y * 64;
    const int tid  = threadIdx.x;
    const int lane = tid & 63;
    const int wave = tid >> 6;
    const int wr = wave >> 1, wc = wave & 1;   // 2x2 waves, each 32x32
    const int quad = lane >> 4, lr = lane & 15;

    if (OUTMODE == 2) {
        // fully-masked tile: attn is exactly 0 here after softmax -> write the
        // FINAL value 0.0f and bail (fused softmax+PV never touches this tile)
        if (n0 >= m0 + 64) {
            float* Cb = (float*)Cv + (long)bz * sC;
            float4 vv = make_float4(0.0f, 0.0f, 0.0f, 0.0f);
            int r = tid >> 2, c = (tid & 3) * 16;
            #pragma unroll
            for (int j = 0; j < 4; j++)
                *(float4*)&Cb[(long)(m0 + r) * ldC + n0 + c + j * 4] = vv;
            return;
        }
    }

    __shared__ __align__(16) f16 Asm[64 * LDSK];
    __shared__ __align__(16) f16 Bsm[64 * LDSK];

    A += (long)bz * sA;
    B += (long)bz * sB;

    float4v acc[2][2];
    #pragma unroll
    for (int i = 0; i < 2; i++)
        #pragma unroll
        for (int j = 0; j < 2; j++) acc[i][j] = (float4v)0.0f;

    int kend = K;
    if (KLIMIT) kend = min(K, m0 + 64);

    const int rA = tid >> 3;           // 0..31 (and +32)
    const int cA = (tid & 7) * 8;      // 0,8,..,56

    for (int k0 = 0; k0 < kend; k0 += BKK) {
        {
            half8 v0 = load8h(&A[(long)(m0 + rA)      * ldA + k0 + cA]);
            half8 v1 = load8h(&A[(long)(m0 + rA + 32) * ldA + k0 + cA]);
            *(half8*)&Asm[ rA       * LDSK + cA] = v0;
            *(half8*)&Asm[(rA + 32) * LDSK + cA] = v1;
        }
        if (BLAYOUT == 0) {
            half8 v0 = load8h(&B[(long)(n0 + rA)      * ldB + k0 + cA]);
            half8 v1 = load8h(&B[(long)(n0 + rA + 32) * ldB + k0 + cA]);
            *(half8*)&Bsm[ rA       * LDSK + cA] = v0;
            *(half8*)&Bsm[(rA + 32) * LDSK + cA] = v1;
        } else {
            half8 v0 = load8h(&B[(long)(k0 + rA)      * ldB + n0 + cA]);
            half8 v1 = load8h(&B[(long)(k0 + rA + 32) * ldB + n0 + cA]);
            #pragma unroll
            for (int j = 0; j < 8; j++) {
                Bsm[(cA + j) * LDSK + rA     ] = v0[j];
                Bsm[(cA + j) * LDSK + rA + 32] = v1[j];
            }
        }
        __syncthreads();

        #pragma unroll
        for (int ks = 0; ks < 2; ks++) {
            half8 af[2], bfv[2];
            #pragma unroll
            for (int mt = 0; mt < 2; mt++)
                af[mt] = *(const half8*)&Asm[(wr * 32 + mt * 16 + lr) * LDSK + ks * 32 + quad * 8];
            #pragma unroll
            for (int nt = 0; nt < 2; nt++)
                bfv[nt] = *(const half8*)&Bsm[(wc * 32 + nt * 16 + lr) * LDSK + ks * 32 + quad * 8];
            #pragma unroll
            for (int mt = 0; mt < 2; mt++)
                #pragma unroll
                for (int nt = 0; nt < 2; nt++)
                    acc[mt][nt] = __builtin_amdgcn_mfma_f32_16x16x32_f16(
                        af[mt], bfv[nt], acc[mt][nt], 0, 0, 0);
        }
        __syncthreads();
    }

    // --- epilogue: C/D layout col=lane&15, row=quad*4+reg (m89-verified) ---
    #pragma unroll
    for (int mt = 0; mt < 2; mt++) {
        #pragma unroll
        for (int nt = 0; nt < 2; nt++) {
            #pragma unroll
            for (int r = 0; r < 4; r++) {
                int row = m0 + wr * 32 + mt * 16 + quad * 4 + r;
                int col = n0 + wc * 32 + nt * 16 + lr;
                float val = acc[mt][nt][r] * scale;
                if (OUTMODE == 0) {
                    f16* Cb = (f16*)Cv + (long)bz * sC;
                    Cb[(long)row * ldC + col] = (f16)val;
                } else if (OUTMODE == 1) {
                    float* Cb = (float*)Cv + (long)bz * sC;
                    Cb[(long)row * ldC + col] = val;
                } else if (OUTMODE == 3) {
                    f16* Cb = (f16*)Cv + (long)bz * sC;
                    Cb[(long)col * ldC + row] = (f16)val;
                } else {
                    float* Cb = (float*)Cv + (long)bz * sC;
                    if (col > row) val = -__builtin_inff();
                    Cb[(long)row * ldC + col] = val;
                }
            }
        }
    }
}

// ---------------------------------------------------------------------------
// Fused softmax + PV. One block = 32 query rows of one head, ALL 512 cols.
// Pass 1: streaming online row max + sum(exp) over the causal k-range.
// Pass 2: per 64-k tile: e = exp(s-m)*invSum -> write attn f32 (OUTPUT 1,
//         in place) -> f16 P tile in LDS -> MFMA with v_sT (B frags straight
//         from global [n][k] layout, L2-resident) -> heads f16.
// Upper-triangle tiles were pre-written 0.0f by the scores quick-path.
// Work-balanced flat grid: blocks c, c+256, c+512, c+768 (round-robin
// co-residents) sum to constant work.
// ---------------------------------------------------------------------------
__launch_bounds__(256)
__global__ void softmax_pv_kernel(float* __restrict__ attn,
                                  const f16* __restrict__ vT,
                                  f16* __restrict__ heads)
{
    int g = blockIdx.x;                  // 0..1023
    int mb, h;
    if (g < 512) { mb = g >> 2;                 h = g & 3; }
    else         { g -= 512; mb = 127 - (g >> 2); h = 4 + (g & 3); }
    const int m0 = mb * 32;
    const int KE = (m0 & ~63) + 64;      // causal k extent, 64-aligned (covers diag tile)

    const int tid  = threadIdx.x;
    const int lane = tid & 63;
    const int wc   = tid >> 6;           // wave 0..3 -> 128-col quarter
    const int quad = lane >> 4, lr = lane & 15;

    __shared__ __align__(16) f16 Psm[32 * LDSK];
    __shared__ float mrow[32], isrow[32];

    float* S = attn + (long)h * LSEQ * LSEQ;
    const int r   = tid >> 3;            // 0..31 (8 threads per row, same wave)
    const int sub = tid & 7;
    float* prow = S + (long)(m0 + r) * LSEQ;

    // ---- pass 1: online row max & sum(exp). -inf entries (diag tile) give
    // exp(-inf - finite) = 0; finite sentinel avoids inf-inf NaN. ----
    float mt = -1e30f, st = 0.0f;
    for (int k = sub * 8; k < KE; k += 64) {
        float4 a = *(const float4*)&prow[k];
        float4 b = *(const float4*)&prow[k + 4];
        float mx = fmaxf(fmaxf(fmaxf(a.x, a.y), fmaxf(a.z, a.w)),
                         fmaxf(fmaxf(b.x, b.y), fmaxf(b.z, b.w)));
        if (mx > mt) { st *= __expf(mt - mx); mt = mx; }
        st += __expf(a.x - mt) + __expf(a.y - mt) + __expf(a.z - mt) + __expf(a.w - mt)
            + __expf(b.x - mt) + __expf(b.y - mt) + __expf(b.z - mt) + __expf(b.w - mt);
    }
    #pragma unroll
    for (int off = 1; off < 8; off <<= 1) {   // combine the 8 lanes of a row
        float mo = __shfl_xor(mt, off);
        float so = __shfl_xor(st, off);
        float mn = fmaxf(mt, mo);
        st = st * __expf(mt - mn) + so * __expf(mo - mn);
        mt = mn;
    }
    if (sub == 0) { mrow[r] = mt; isrow[r] = 1.0f / st; }
    __syncthreads();
    const float m_r = mrow[r], is_r = isrow[r];

    float4v acc[2][8];
    #pragma unroll
    for (int i = 0; i < 2; i++)
        #pragma unroll
        for (int j = 0; j < 8; j++) acc[i][j] = (float4v)0.0f;

    // ---- pass 2 ----
    for (int kt = 0; kt < KE; kt += 64) {
        float* pk = prow + kt + sub * 8;
        float4 a = *(const float4*)pk;
        float4 b = *(const float4*)(pk + 4);
        a.x = __expf(a.x - m_r) * is_r;  a.y = __expf(a.y - m_r) * is_r;
        a.z = __expf(a.z - m_r) * is_r;  a.w = __expf(a.w - m_r) * is_r;
        b.x = __expf(b.x - m_r) * is_r;  b.y = __expf(b.y - m_r) * is_r;
        b.z = __expf(b.z - m_r) * is_r;  b.w = __expf(b.w - m_r) * is_r;
        *(float4*)pk = a;                 // final attn values (OUTPUT 1)
        *(float4*)(pk + 4) = b;
        half8 hp;
        hp[0] = (f16)a.x; hp[1] = (f16)a.y; hp[2] = (f16)a.z; hp[3] = (f16)a.w;
        hp[4] = (f16)b.x; hp[5] = (f16)b.y; hp[6] = (f16)b.z; hp[7] = (f16)b.w;
        *(half8*)&Psm[r * LDSK + sub * 8] = hp;
        __syncthreads();

        half8 af[2][2];
        #pragma unroll
        for (int m2 = 0; m2 < 2; m2++)
            #pragma unroll
            for (int ks = 0; ks < 2; ks++)
                af[m2][ks] = *(const half8*)&Psm[(m2 * 16 + lr) * LDSK + ks * 32 + quad * 8];

        const f16* vb = vT + ((long)h * DMODEL + wc * 128) * LSEQ + kt + quad * 8;
        #pragma unroll
        for (int nt = 0; nt < 8; nt++) {
            const f16* vp = vb + (long)(nt * 16 + lr) * LSEQ;
            half8 b0 = *(const half8*)vp;          // k = kt + quad*8 .. +8
            half8 b1 = *(const half8*)(vp + 32);   // k = kt + 32 + quad*8 .. +8
            acc[0][nt] = __builtin_amdgcn_mfma_f32_16x16x32_f16(af[0][0], b0, acc[0][nt], 0, 0, 0);
            acc[0][nt] = __builtin_amdgcn_mfma_f32_16x16x32_f16(af[0][1], b1, acc[0][nt], 0, 0, 0);
            acc[1][nt] = __builtin_amdgcn_mfma_f32_16x16x32_f16(af[1][0], b0, acc[1][nt], 0, 0, 0);
            acc[1][nt] = __builtin_amdgcn_mfma_f32_16x16x32_f16(af[1][1], b1, acc[1][nt], 0, 0, 0);
        }
        __syncthreads();
    }

    // ---- epilogue: heads[:, h*512 + col] ----
    #pragma unroll
    for (int m2 = 0; m2 < 2; m2++)
        #pragma unroll
        for (int nt = 0; nt < 8; nt++)
            #pragma unroll
            for (int rr = 0; rr < 4; rr++) {
                int row = m0 + m2 * 16 + quad * 4 + rr;
                int col = wc * 128 + nt * 16 + lr;
                heads[(long)row * (NHEAD * DMODEL) + h * DMODEL + col] = (f16)acc[m2][nt][rr];
            }
}

// ---------------------------------------------------------------------------
// Epilogue: x = lin(f32, in out region) + proj_b + q -> LayerNorm(512)
// ---------------------------------------------------------------------------
__launch_bounds__(256)
__global__ void ln_kernel(float* lin_out,
                          const float* __restrict__ qin,
                          const float* __restrict__ bias,
                          const float* __restrict__ gamma,
                          const float* __restrict__ beta)
{
    __shared__ float red[8];
    const int l = blockIdx.x;
    const int tid = threadIdx.x;
    float* pl = lin_out + (long)l * DMODEL;
    const float* pq = qin + (long)l * DMODEL;

    float x0 = pl[tid]       + pq[tid]       + bias[tid];
    float x1 = pl[tid + 256] + pq[tid + 256] + bias[tid + 256];
    float sum = x0 + x1, sq = x0 * x0 + x1 * x1;
    #pragma unroll
    for (int off = 32; off > 0; off >>= 1) {
        sum += __shfl_down(sum, off);
        sq  += __shfl_down(sq,  off);
    }
    if ((tid & 63) == 0) { red[tid >> 6] = sum; red[4 + (tid >> 6)] = sq; }
    __syncthreads();
    const float S  = red[0] + red[1] + red[2] + red[3];
    const float Q2 = red[4] + red[5] + red[6] + red[7];
    const float mu = S * (1.0f / DMODEL);
    const float var = Q2 * (1.0f / DMODEL) - mu * mu;
    const float rstd = rsqrtf(var + 1e-5f);

    pl[tid]       = (x0 - mu) * rstd * gamma[tid]       + beta[tid];
    pl[tid + 256] = (x1 - mu) * rstd * gamma[tid + 256] + beta[tid + 256];
}

// ---------------------------------------------------------------------------
extern "C" void kernel_launch(void* const* d_in, const int* in_sizes, int n_in,
                              void* d_out, int out_size, void* d_ws, size_t ws_size,
                              hipStream_t stream)
{
    const float* q      = (const float*)d_in[0];
    const float* k      = (const float*)d_in[1];
    const float* v      = (const float*)d_in[2];
    // d_in[3] = attn_mask: causal by construction; not needed
    const float* w_qs   = (const float*)d_in[4];
    const float* w_ks   = (const float*)d_in[5];
    const float* w_vs   = (const float*)d_in[6];
    const float* proj_w = (const float*)d_in[7];
    const float* proj_b = (const float*)d_in[8];
    const float* gamma  = (const float*)d_in[9];
    const float* beta   = (const float*)d_in[10];

    float* out  = (float*)d_out;                           // 4096*512 f32
    float* attn = (float*)d_out + (long)LSEQ * DMODEL;     // 8*4096*4096 f32

    const long PROJ = (long)NHEAD * LSEQ * DMODEL;         // 16,777,216 elems
    char* ws = (char*)d_ws;
    f16* q_s   = (f16*)ws;  ws += PROJ * 2;
    f16* k_s   = (f16*)ws;  ws += PROJ * 2;
    f16* v_sT  = (f16*)ws;  ws += PROJ * 2;                // TRANSPOSED [H][D][L]
    f16* heads = (f16*)ws;                                 // 4096 x 4096 f16

    f16* w2 = (f16*)d_out;  // 8*512*512 f16 = 4 MiB scratch inside out region

    const dim3 blk(256);
    const float inv_temper = 0.044194173824159216f;        // 1/sqrt(512)
    const long sW  = (long)DMODEL * DMODEL;
    const long sT  = (long)LSEQ * DMODEL;

    // --- folded double projection: W2_h = W_h @ W_h, then X @ W2 ---
    const dim3 gW(DMODEL / 64, DMODEL / 64, NHEAD);
    const dim3 gP(DMODEL / 64, LSEQ / 64, NHEAD);
    gemm64_kernel<float, float, 1, 0, false><<<gW, blk, 0, stream>>>(w_qs, w_qs, w2,  DMODEL, DMODEL, DMODEL, DMODEL, DMODEL, DMODEL, sW, sW, sW, 1.0f);
    gemm64_kernel<float, f16,   1, 0, false><<<gP, blk, 0, stream>>>(q,    w2,   q_s, LSEQ,   DMODEL, DMODEL, DMODEL, DMODEL, DMODEL, 0,  sW, sT, 1.0f);
    gemm64_kernel<float, float, 1, 0, false><<<gW, blk, 0, stream>>>(w_ks, w_ks, w2,  DMODEL, DMODEL, DMODEL, DMODEL, DMODEL, DMODEL, sW, sW, sW, 1.0f);
    gemm64_kernel<float, f16,   1, 0, false><<<gP, blk, 0, stream>>>(k,    w2,   k_s, LSEQ,   DMODEL, DMODEL, DMODEL, DMODEL, DMODEL, 0,  sW, sT, 1.0f);
    gemm64_kernel<float, float, 1, 0, false><<<gW, blk, 0, stream>>>(w_vs, w_vs, w2,  DMODEL, DMODEL, DMODEL, DMODEL, DMODEL, DMODEL, sW, sW, sW, 1.0f);
    // v projection writes TRANSPOSED (OUTMODE=3): v_sT[h][d][l], ldC = LSEQ
    gemm64_kernel<float, f16,   1, 3, false><<<gP, blk, 0, stream>>>(v,    w2,   v_sT, LSEQ,  DMODEL, DMODEL, DMODEL, DMODEL, LSEQ,   0,  sW, sT, 1.0f);

    // --- scores: S = (q_s k_s^T) / temper; quick-path tiles = 0.0f (final),
    //     diagonal tiles carry -inf above diag for the fused softmax ---
    const dim3 gS(LSEQ / 64, LSEQ / 64, NHEAD);
    gemm64_kernel<f16, f16, 0, 2, false><<<gS, blk, 0, stream>>>(
        q_s, k_s, attn, LSEQ, LSEQ, DMODEL,
        DMODEL, DMODEL, LSEQ,
        sT, sT, (long)LSEQ * LSEQ, inv_temper);

    // --- fused softmax + PV: writes attn f32 (OUTPUT 1) and heads f16 ---
    softmax_pv_kernel<<<dim3(128 * NHEAD), blk, 0, stream>>>(attn, v_sT, heads);

    // --- final projection: lin = heads @ proj_w^T, f32 into out region ---
    gemm64_kernel<f16, float, 0, 1, false><<<dim3(DMODEL / 64, LSEQ / 64, 1), blk, 0, stream>>>(
        heads, proj_w, out, LSEQ, DMODEL, NHEAD * DMODEL,
        NHEAD * DMODEL, NHEAD * DMODEL, DMODEL,
        0, 0, 0, 1.0f);

    // --- bias + residual + LayerNorm in place, f32 (writes OUTPUT 0) ---
    ln_kernel<<<dim3(LSEQ), blk, 0, stream>>>(out, q, proj_b, gamma, beta);
}